// Round 2
// baseline (113.376 us; speedup 1.0000x reference)
//
#include <hip/hip_runtime.h>
#include <math.h>

// x: [B=16, C=2048, H=64, W=64] fp32. H*W = 4096 contiguous floats per channel.
// Kernel 1: ONE WAVE per channel. 8192 blocks x 256 threads (4 waves/block).
// Each lane: 16x float4 coalesced loads (lots of ILP), then 6-shuffle butterfly.
// No LDS, no __syncthreads.
__global__ __launch_bounds__(256) void pool_kernel(const float* __restrict__ x,
                                                   float* __restrict__ mean_out,
                                                   float* __restrict__ max_out) {
    const int wave = threadIdx.x >> 6;
    const int lane = threadIdx.x & 63;
    const int bc = blockIdx.x * 4 + wave;            // 0..32767 (b*2048 + c)
    const float4* base4 = (const float4*)(x + (size_t)bc * 4096);

    float s = 0.f;
    float m = -INFINITY;
#pragma unroll
    for (int i = 0; i < 16; ++i) {                   // 1024 float4 / 64 lanes
        float4 v = base4[lane + i * 64];
        s += (v.x + v.y) + (v.z + v.w);
        m = fmaxf(m, fmaxf(fmaxf(v.x, v.y), fmaxf(v.z, v.w)));
    }
    // wave64 butterfly reduce (pure shuffles)
#pragma unroll
    for (int off = 32; off > 0; off >>= 1) {
        s += __shfl_down(s, off, 64);
        m = fmaxf(m, __shfl_down(m, off, 64));
    }
    if (lane == 0) {
        mean_out[bc] = s * (1.0f / 4096.0f);
        max_out[bc]  = m;
    }
}

// Kernel 2: SE branch on [B, K=256] with Kr=128. One block per batch element.
// f[k]   = sum_o pooled[b][k*8+o] * w_ch[o]
// h[j]   = relu(<f_avg, w1[j]>) + relu(<f_max, w1[j]>)   (w2 is linear -> sum ok)
// y[k]   = sigmoid(<h, w2[k]>)
// out[b][k*8+o] = y[k]
__global__ __launch_bounds__(256) void se_kernel(const float* __restrict__ mean_in,
                                                 const float* __restrict__ max_in,
                                                 const float* __restrict__ w_ch,
                                                 const float* __restrict__ w1,
                                                 const float* __restrict__ w2,
                                                 float* __restrict__ out) {
    const int b = blockIdx.x;        // 0..15
    const int tid = threadIdx.x;     // 0..255

    __shared__ float fa[256];
    __shared__ float fm[256];
    __shared__ float hs[128];
    __shared__ float wc[8];
    if (tid < 8) wc[tid] = w_ch[tid];
    __syncthreads();

    {   // orientation contraction: each thread owns one k
        const float* pa = mean_in + b * 2048 + tid * 8;
        const float* pm = max_in  + b * 2048 + tid * 8;
        float sa = 0.f, sx = 0.f;
#pragma unroll
        for (int o = 0; o < 8; ++o) {
            sa += pa[o] * wc[o];
            sx += pm[o] * wc[o];
        }
        fa[tid] = sa;
        fm[tid] = sx;
    }
    __syncthreads();

    if (tid < 128) {                 // first matvec, both branches share w1 read
        const float* w1r = w1 + tid * 256;
        float sa = 0.f, sx = 0.f;
        for (int k = 0; k < 256; ++k) {
            float w = w1r[k];
            sa += fa[k] * w;
            sx += fm[k] * w;
        }
        hs[tid] = fmaxf(sa, 0.f) + fmaxf(sx, 0.f);
    }
    __syncthreads();

    {   // second matvec + sigmoid + 8-way repeat
        const float* w2r = w2 + tid * 128;
        float s = 0.f;
        for (int j = 0; j < 128; ++j) s += hs[j] * w2r[j];
        float y = 1.0f / (1.0f + expf(-s));
        float4 v = make_float4(y, y, y, y);
        float4* o4 = (float4*)(out + b * 2048 + tid * 8);
        o4[0] = v;
        o4[1] = v;
    }
}

extern "C" void kernel_launch(void* const* d_in, const int* in_sizes, int n_in,
                              void* d_out, int out_size, void* d_ws, size_t ws_size,
                              hipStream_t stream) {
    const float* x    = (const float*)d_in[0];   // [16,2048,64,64]
    const float* w_ch = (const float*)d_in[1];   // [8]
    const float* w1   = (const float*)d_in[2];   // [128,256]
    const float* w2   = (const float*)d_in[3];   // [256,128]
    float* out = (float*)d_out;                  // [16,2048] (as [B,C,1,1])

    float* mean_ws = (float*)d_ws;               // 32768 floats
    float* max_ws  = mean_ws + 32768;            // 32768 floats

    pool_kernel<<<8192, 256, 0, stream>>>(x, mean_ws, max_ws);
    se_kernel<<<16, 256, 0, stream>>>(mean_ws, max_ws, w_ch, w1, w2, out);
}

// Round 3
// 99.343 us; speedup vs baseline: 1.1413x; 1.1413x over previous
//
#include <hip/hip_runtime.h>
#include <math.h>

typedef float v4f __attribute__((ext_vector_type(4)));

// x: [B=16, C=2048, H=64, W=64] fp32. H*W = 4096 contiguous floats per channel.
// Persistent pool kernel: 2048 blocks x 256 threads (4 waves/block -> 8192 waves).
// Each wave reduces 4 consecutive channels; per channel 2 batches of 8 float4
// loads (keeps live-load VGPRs at 32 -> total < 64 -> 8 waves/SIMD occupancy).
// Pure-shuffle wave reduce, no LDS, no barriers. Nontemporal loads (streaming,
// x is 512MB > L3).
__global__ __launch_bounds__(256) void pool_kernel(const float* __restrict__ x,
                                                   float* __restrict__ mean_out,
                                                   float* __restrict__ max_out) {
    const int wave_g = (blockIdx.x << 2) + (threadIdx.x >> 6);   // 0..8191
    const int lane = threadIdx.x & 63;

#pragma unroll 1
    for (int i = 0; i < 4; ++i) {
        const int bc = (wave_g << 2) + i;                        // 0..32767
        const v4f* p4 = (const v4f*)(x + (size_t)bc * 4096);

        float s = 0.f;
        float m = -INFINITY;
#pragma unroll 1
        for (int batch = 0; batch < 2; ++batch) {
            v4f v[8];
#pragma unroll
            for (int j = 0; j < 8; ++j)
                v[j] = __builtin_nontemporal_load(&p4[lane + (batch * 8 + j) * 64]);
#pragma unroll
            for (int j = 0; j < 8; ++j) {
                s += (v[j].x + v[j].y) + (v[j].z + v[j].w);
                m = fmaxf(m, fmaxf(fmaxf(v[j].x, v[j].y), fmaxf(v[j].z, v[j].w)));
            }
        }
        // wave64 butterfly reduce (pure shuffles)
#pragma unroll
        for (int off = 32; off > 0; off >>= 1) {
            s += __shfl_down(s, off, 64);
            m = fmaxf(m, __shfl_down(m, off, 64));
        }
        if (lane == 0) {
            mean_out[bc] = s * (1.0f / 4096.0f);
            max_out[bc]  = m;
        }
    }
}

// Kernel 2: SE branch on [B, K=256] with Kr=128. One block per batch element.
// f[k]   = sum_o pooled[b][k*8+o] * w_ch[o]
// h[j]   = relu(<f_avg, w1[j]>) + relu(<f_max, w1[j]>)   (w2 linear -> sum ok)
// y[k]   = sigmoid(<h, w2[k]>)
// out[b][k*8+o] = y[k]
__global__ __launch_bounds__(256) void se_kernel(const float* __restrict__ mean_in,
                                                 const float* __restrict__ max_in,
                                                 const float* __restrict__ w_ch,
                                                 const float* __restrict__ w1,
                                                 const float* __restrict__ w2,
                                                 float* __restrict__ out) {
    const int b = blockIdx.x;        // 0..15
    const int tid = threadIdx.x;     // 0..255

    __shared__ float fa[256];
    __shared__ float fm[256];
    __shared__ float hs[128];
    __shared__ float wc[8];
    if (tid < 8) wc[tid] = w_ch[tid];
    __syncthreads();

    {   // orientation contraction: each thread owns one k
        const float* pa = mean_in + b * 2048 + tid * 8;
        const float* pm = max_in  + b * 2048 + tid * 8;
        float sa = 0.f, sx = 0.f;
#pragma unroll
        for (int o = 0; o < 8; ++o) {
            sa += pa[o] * wc[o];
            sx += pm[o] * wc[o];
        }
        fa[tid] = sa;
        fm[tid] = sx;
    }
    __syncthreads();

    if (tid < 128) {                 // first matvec, both branches share w1 read
        const float* w1r = w1 + tid * 256;
        float sa = 0.f, sx = 0.f;
        for (int k = 0; k < 256; ++k) {
            float w = w1r[k];
            sa += fa[k] * w;
            sx += fm[k] * w;
        }
        hs[tid] = fmaxf(sa, 0.f) + fmaxf(sx, 0.f);
    }
    __syncthreads();

    {   // second matvec + sigmoid + 8-way repeat
        const float* w2r = w2 + tid * 128;
        float s = 0.f;
        for (int j = 0; j < 128; ++j) s += hs[j] * w2r[j];
        float y = 1.0f / (1.0f + expf(-s));
        float4 v = make_float4(y, y, y, y);
        float4* o4 = (float4*)(out + b * 2048 + tid * 8);
        o4[0] = v;
        o4[1] = v;
    }
}

extern "C" void kernel_launch(void* const* d_in, const int* in_sizes, int n_in,
                              void* d_out, int out_size, void* d_ws, size_t ws_size,
                              hipStream_t stream) {
    const float* x    = (const float*)d_in[0];   // [16,2048,64,64]
    const float* w_ch = (const float*)d_in[1];   // [8]
    const float* w1   = (const float*)d_in[2];   // [128,256]
    const float* w2   = (const float*)d_in[3];   // [256,128]
    float* out = (float*)d_out;                  // [16,2048] (as [B,C,1,1])

    float* mean_ws = (float*)d_ws;               // 32768 floats
    float* max_ws  = mean_ws + 32768;            // 32768 floats

    pool_kernel<<<2048, 256, 0, stream>>>(x, mean_ws, max_ws);
    se_kernel<<<16, 256, 0, stream>>>(mean_ws, max_ws, w_ch, w1, w2, out);
}